// Round 10
// baseline (682.733 us; speedup 1.0000x reference)
//
#include <hip/hip_runtime.h>
#include <math.h>

// CriticBatchNet: NNConv(+edge-net) + GRU x6, Set2Set x6, LSTM head.
// msg[e] = out[src]@W_e[e], W_e[e]=hidden[e]@e_w2+b2
//   => segsum_dst(msg)[m,f] = sum_kd S[m,kd]*Vr[kd,f],
//      S[m,k*32+d] = sum_{e:dst=m} hidden[e,k]*out[src_e,d]
//      S[m,1024+j] = sum_{e:dst=m} out[src_e,j]   (bias rows)
// v10: 512 threads, __launch_bounds__(512,8) -> VGPR cap 64 (NOT v9's 32),
//      4 blocks/CU, 32 waves/CU. Sequential 2-node phase 1 (fits 64 regs),
//      bf16-S plane in LDS (38KB), 4-MFMA phase 2 (direct short8 A read),
//      float4 transposed-weight epilogue.

typedef __attribute__((ext_vector_type(8))) short short8;
typedef __attribute__((ext_vector_type(4))) float f32x4;
typedef __attribute__((ext_vector_type(16))) float f32x16;

#define SPADU 1064   // ushort stride per S row (1056 + pad, 8-aligned)

__device__ __forceinline__ float sigf(float x){ return 1.f/(1.f+expf(-x)); }

__device__ __forceinline__ unsigned packsplit(float v){
  unsigned uv = __float_as_uint(v);
  float res = v - __uint_as_float(uv & 0xFFFF0000u);
  return (uv & 0xFFFF0000u) | (__float_as_uint(res) >> 16);
}

__device__ __forceinline__ unsigned short bf16rn(float v){
  unsigned u = __float_as_uint(v);
  return (unsigned short)((u + 0x8000u) >> 16);
}

// fused: zero counts/cursor, lin0 (f32+packed), permW2split, gruT/rootT
__global__ void k_pre(const float* __restrict__ x, const float* __restrict__ w,
                      const float* __restrict__ b,
                      const float* __restrict__ e_w2, const float* __restrict__ e_b2,
                      const float* __restrict__ g_wih, const float* __restrict__ g_whh,
                      const float* __restrict__ root_w,
                      float* __restrict__ cur, unsigned* __restrict__ curq,
                      unsigned short* __restrict__ VrT_hi,
                      unsigned short* __restrict__ VrT_lo,
                      float* __restrict__ gruT, float* __restrict__ rootT,
                      int* __restrict__ counts, int* __restrict__ cursor, int N){
  int i = blockIdx.x*blockDim.x + threadIdx.x;
  if (i < N){ counts[i]=0; cursor[i]=0; }
  if (i < N*32){
    int n = i>>5, d = i&31;
    float acc = b[d];
    acc = fmaf(x[n*3+0], w[0*32+d], acc);
    acc = fmaf(x[n*3+1], w[1*32+d], acc);
    acc = fmaf(x[n*3+2], w[2*32+d], acc);
    float v = fmaxf(acc, 0.f);
    cur[i] = v;
    curq[i] = packsplit(v);
  }
  if (i < 1056*32){
    int f = i & 31, kd = i >> 5;
    float v = (kd < 1024) ? e_w2[(kd>>5)*1024 + (kd&31)*32 + f]
                          : e_b2[(kd-1024)*32 + f];
    unsigned ub = __float_as_uint(v);
    float res = v - __uint_as_float(ub & 0xFFFF0000u);
    VrT_hi[f*1056 + kd] = (unsigned short)(ub >> 16);
    VrT_lo[f*1056 + kd] = (unsigned short)(__float_as_uint(res) >> 16);
  }
  if (i < 3072){            // gruT[0..3071] = wih^T : [(g*32+f)*32 + k]
    int fp = i >> 5, k = i & 31;
    gruT[i] = g_wih[k*96 + fp];
  } else if (i < 6144){     // gruT[3072..] = whh^T
    int j = i - 3072; int fp = j >> 5, k = j & 31;
    gruT[i] = g_whh[k*96 + fp];
  }
  if (i >= 6144 && i < 7168){ // rootT[f*32+k] = root_w[k*32+f]
    int j = i - 6144; int f = j >> 5, k = j & 31;
    rootT[j] = root_w[k*32 + f];
  }
}

__global__ void k_count(const int* __restrict__ dst, int* __restrict__ counts, int E){
  int i = blockIdx.x*blockDim.x + threadIdx.x;
  if (i < E) atomicAdd(&counts[dst[i]], 1);
}

// 3-stage parallel exclusive scan
__global__ void k_scanA(const int* __restrict__ counts, int* __restrict__ row_off,
                        int* __restrict__ part, int N){
  __shared__ int buf[256];
  int b = blockIdx.x, t = threadIdx.x, base = b*256;
  int v = (base + t < N) ? counts[base + t] : 0;
  buf[t] = v; __syncthreads();
  #pragma unroll
  for (int off = 1; off < 256; off <<= 1){
    int tmp = (t >= off) ? buf[t-off] : 0;
    __syncthreads();
    buf[t] += tmp;
    __syncthreads();
  }
  if (base + t < N) row_off[base + t] = buf[t] - v;
  if (t == 255) part[b] = buf[255];
}

__global__ void k_scanB(int* __restrict__ part, int* __restrict__ row_off,
                        int nch, int N){
  __shared__ int buf[256];
  int t = threadIdx.x;
  int v = (t < nch) ? part[t] : 0;
  buf[t] = v; __syncthreads();
  #pragma unroll
  for (int off = 1; off < 256; off <<= 1){
    int tmp = (t >= off) ? buf[t-off] : 0;
    __syncthreads();
    buf[t] += tmp;
    __syncthreads();
  }
  if (t < nch) part[t] = buf[t] - v;
  if (t == 255) row_off[N] = buf[255];
}

__global__ void k_scanC(int* __restrict__ row_off, const int* __restrict__ part, int N){
  int i = blockIdx.x*256 + threadIdx.x;
  if (i < N) row_off[i] += part[blockIdx.x];
}

__global__ void k_scatter(const int* __restrict__ dst, const int* __restrict__ row_off,
                          int* __restrict__ cursor, int* __restrict__ eid, int E){
  int i = blockIdx.x*blockDim.x + threadIdx.x;
  if (i < E){
    int dn = dst[i];
    int pos = row_off[dn] + atomicAdd(&cursor[dn], 1);
    eid[pos] = i;
  }
}

// fused: hidq[p] = packsplit(relu(ea[eid[p]] @ e_w1 + e_b1)), srcp[p] = src[eid[p]]
__global__ void k_edgeCSR(const int* __restrict__ eid, const int* __restrict__ src,
                          const float* __restrict__ ea, const float* __restrict__ w,
                          const float* __restrict__ b, unsigned* __restrict__ hidq,
                          int* __restrict__ srcp, int E){
  int i = blockIdx.x*blockDim.x + threadIdx.x;
  if (i >= E*32) return;
  int p = i>>5, d = i&31;
  int e = eid[p];
  const float4* ea4 = (const float4*)ea;
  float4 v = ea4[e];
  float acc = b[d];
  acc = fmaf(v.x, w[0*32+d], acc);
  acc = fmaf(v.y, w[1*32+d], acc);
  acc = fmaf(v.z, w[2*32+d], acc);
  acc = fmaf(v.w, w[3*32+d], acc);
  hidq[i] = packsplit(fmaxf(acc, 0.f));
  if (d == 0) srcp[p] = src[e];
}

// Fused per-iteration kernel: 512 threads, 8 waves, 16 nodes (2/wave seq).
__global__ __launch_bounds__(512, 8) void k_iter(
    const int* __restrict__ row_off, const int* __restrict__ srcp,
    const unsigned* __restrict__ hidq, const unsigned* __restrict__ curq_in,
    const float* __restrict__ cur_in,
    const unsigned short* __restrict__ VrT_hi, const unsigned short* __restrict__ VrT_lo,
    const float* __restrict__ gruT, const float* __restrict__ rootT,
    const float* __restrict__ conv_b,
    const float* __restrict__ bih, const float* __restrict__ bhh,
    float* __restrict__ cur_out, unsigned* __restrict__ curq_out, int N){
  __shared__ __align__(16) unsigned short s_hi[16*SPADU]; // bf16 S rows (34KB)
  __shared__ float htile[16*32];
  __shared__ float mtile[16*32];
  int nb = blockIdx.x*16;
  int t = threadIdx.x;
  int w = t >> 6, l = t & 63, col = l & 31, half = l >> 5;

  // stage htile early — overlaps phase 1
  {
    int node = t >> 5, f = t & 31;
    int n2 = nb + node;
    htile[t] = (n2 < N) ? cur_in[n2*32 + f] : 0.f;
  }

  // ---- phase 1: 2 nodes per wave (sequential), MFMA outer products ----
  #pragma unroll
  for (int q = 0; q < 2; ++q){
    int n = nb + 2*w + q;
    f32x16 S = {0.f,0.f,0.f,0.f,0.f,0.f,0.f,0.f,0.f,0.f,0.f,0.f,0.f,0.f,0.f,0.f};
    float aex = 0.f;
    int lo = 0, hi = 0;
    if (n < N){ lo = row_off[n]; hi = row_off[n+1]; }
    for (int p0 = lo; p0 < hi; p0 += 16){
      short8 Ah, Al, Bh, Bl;
      #pragma unroll
      for (int j=0;j<8;++j){
        int pp = p0 + 8*half + j;
        bool val = pp < hi;
        int idx = val ? pp : 0;
        unsigned hp = hidq[idx*32 + col];
        unsigned o  = curq_in[srcp[idx]*32 + col];
        hp = val ? hp : 0u;
        o  = val ? o  : 0u;
        Ah[j] = (short)(hp >> 16);
        Al[j] = (short)(hp & 0xffffu);
        Bh[j] = (short)(o >> 16);
        Bl[j] = (short)(o & 0xffffu);
        aex += __uint_as_float(o & 0xFFFF0000u) + __uint_as_float(o << 16);
      }
      S = __builtin_amdgcn_mfma_f32_32x32x16_bf16(Ah, Bh, S, 0,0,0);
      S = __builtin_amdgcn_mfma_f32_32x32x16_bf16(Al, Bh, S, 0,0,0);
      S = __builtin_amdgcn_mfma_f32_32x32x16_bf16(Ah, Bl, S, 0,0,0);
    }
    // write bf16 S row: C layout row k=(i&3)+8*(i>>2)+4*half, col=d
    unsigned short* sp = &s_hi[(2*w+q)*SPADU];
    #pragma unroll
    for (int i=0;i<16;++i){
      int k = (i&3) + 8*(i>>2) + 4*half;
      sp[k*32 + col] = bf16rn(S[i]);
    }
    aex += __shfl_xor(aex, 32, 64);
    if (l < 32) sp[1024 + l] = bf16rn(aex);
  }
  __syncthreads();

  // ---- phase 2: C[m][f] = sum_kd S[m][kd]*Vr[kd][f], 33 K-steps / 8 waves ----
  int fc = l & 15, hq = l >> 4;
  {
    const unsigned short* arow = &s_hi[fc*SPADU];
    const unsigned short* bh0p = VrT_hi + fc*1056;
    const unsigned short* bl0p = VrT_lo + fc*1056;
    const unsigned short* bh1p = VrT_hi + (16+fc)*1056;
    const unsigned short* bl1p = VrT_lo + (16+fc)*1056;
    f32x4 acc0 = {0.f,0.f,0.f,0.f}, acc1 = {0.f,0.f,0.f,0.f};
    int s_lo = (w*33) >> 3, s_hiS = ((w+1)*33) >> 3;
    for (int st = s_lo; st < s_hiS; ++st){
      int kb = st*32 + hq*8;
      short8 Ah  = *(const short8*)(arow + kb);     // direct bf16 A fragment
      short8 bh0 = *(const short8*)(bh0p + kb);
      short8 bl0 = *(const short8*)(bl0p + kb);
      short8 bh1 = *(const short8*)(bh1p + kb);
      short8 bl1 = *(const short8*)(bl1p + kb);
      acc0 = __builtin_amdgcn_mfma_f32_16x16x32_bf16(Ah, bh0, acc0, 0,0,0);
      acc0 = __builtin_amdgcn_mfma_f32_16x16x32_bf16(Ah, bl0, acc0, 0,0,0);
      acc1 = __builtin_amdgcn_mfma_f32_16x16x32_bf16(Ah, bh1, acc1, 0,0,0);
      acc1 = __builtin_amdgcn_mfma_f32_16x16x32_bf16(Ah, bl1, acc1, 0,0,0);
    }
    __syncthreads();                     // all s_hi reads done
    float* pbuf = (float*)s_hi;          // reuse: [w][m(16)][32] = 16KB
    #pragma unroll
    for (int i=0;i<4;++i){
      int m = hq*4 + i;
      pbuf[(w*16 + m)*32 + fc]      = acc0[i];
      pbuf[(w*16 + m)*32 + 16 + fc] = acc1[i];
    }
  }
  __syncthreads();

  // ---- epilogue: reduce partials, root+relu -> m, then GRU ----
  int node = t >> 5, f = t & 31;
  int n2 = nb + node;
  const float* pbuf = (const float*)s_hi;
  if (n2 < N){
    float msum = 0.f;
    #pragma unroll
    for (int w2=0; w2<8; ++w2) msum += pbuf[(w2*16 + node)*32 + f];
    float deg = (float)max(row_off[n2+1] - row_off[n2], 1);
    float rt = 0.f;
    const float4* rT4 = (const float4*)(rootT + f*32);
    const float4* h4  = (const float4*)(htile + node*32);
    #pragma unroll
    for (int k4=0;k4<8;++k4){
      float4 wv = rT4[k4]; float4 hv = h4[k4];
      rt = fmaf(hv.x, wv.x, rt); rt = fmaf(hv.y, wv.y, rt);
      rt = fmaf(hv.z, wv.z, rt); rt = fmaf(hv.w, wv.w, rt);
    }
    mtile[node*32 + f] = fmaxf(msum/deg + rt + conv_b[f], 0.f);
  }
  __syncthreads();
  if (n2 < N){
    float gr = bih[f], gz = bih[32+f], gn = bih[64+f];
    float hr = bhh[f], hz = bhh[32+f], hn = bhh[64+f];
    const float4* m4 = (const float4*)(mtile + node*32);
    const float4* h4 = (const float4*)(htile + node*32);
    const float4* w0 = (const float4*)(gruT + (0*32+f)*32);
    const float4* w1 = (const float4*)(gruT + (1*32+f)*32);
    const float4* w2 = (const float4*)(gruT + (2*32+f)*32);
    const float4* u0 = (const float4*)(gruT + 3072 + (0*32+f)*32);
    const float4* u1 = (const float4*)(gruT + 3072 + (1*32+f)*32);
    const float4* u2 = (const float4*)(gruT + 3072 + (2*32+f)*32);
    #pragma unroll
    for (int k4=0;k4<8;++k4){
      float4 mv = m4[k4], hv = h4[k4];
      float4 a0 = w0[k4], a1 = w1[k4], a2 = w2[k4];
      float4 b0 = u0[k4], b1 = u1[k4], b2 = u2[k4];
      gr = fmaf(mv.x,a0.x,gr); gr = fmaf(mv.y,a0.y,gr); gr = fmaf(mv.z,a0.z,gr); gr = fmaf(mv.w,a0.w,gr);
      gz = fmaf(mv.x,a1.x,gz); gz = fmaf(mv.y,a1.y,gz); gz = fmaf(mv.z,a1.z,gz); gz = fmaf(mv.w,a1.w,gz);
      gn = fmaf(mv.x,a2.x,gn); gn = fmaf(mv.y,a2.y,gn); gn = fmaf(mv.z,a2.z,gn); gn = fmaf(mv.w,a2.w,gn);
      hr = fmaf(hv.x,b0.x,hr); hr = fmaf(hv.y,b0.y,hr); hr = fmaf(hv.z,b0.z,hr); hr = fmaf(hv.w,b0.w,hr);
      hz = fmaf(hv.x,b1.x,hz); hz = fmaf(hv.y,b1.y,hz); hz = fmaf(hv.z,b1.z,hz); hz = fmaf(hv.w,b1.w,hz);
      hn = fmaf(hv.x,b2.x,hn); hn = fmaf(hv.y,b2.y,hn); hn = fmaf(hv.z,b2.z,hn); hn = fmaf(hv.w,b2.w,hn);
    }
    float r = sigf(gr + hr);
    float z = sigf(gz + hz);
    float nn2 = tanhf(gn + r*hn);
    float hcur = htile[node*32 + f];
    float nv = (1.f - z)*nn2 + z*hcur;
    cur_out[n2*32 + f] = nv;
    curq_out[n2*32 + f] = packsplit(nv);
  }
}

// Set2Set x6 + memory LSTM + FC head; one 512-thread block per graph.
#define S2S_CAP 480
__global__ __launch_bounds__(512) void k_s2s(
    const float* __restrict__ cur,
    const float* __restrict__ wi, const float* __restrict__ wh, const float* __restrict__ sb,
    const float* __restrict__ mwi, const float* __restrict__ mwh, const float* __restrict__ mb,
    const float* __restrict__ hx, const float* __restrict__ cx,
    const float* __restrict__ f1w, const float* __restrict__ f1b,
    const float* __restrict__ f2w, const float* __restrict__ f2b,
    float* __restrict__ out, int N, int G){
  int g = blockIdx.x, t = threadIdx.x;
  int lo = (int)(((long long)g*N + G - 1)/G);
  int hi = (int)(((long long)(g+1)*N + G - 1)/G);
  int cnt = hi - lo;
  __shared__ float curL[S2S_CAP*33];
  __shared__ float wiL[96*128];
  __shared__ float ebuf[S2S_CAP];
  __shared__ float qh[96];
  __shared__ float csS[32];
  __shared__ float gbuf[128];
  __shared__ float pbuf4[4][128];
  __shared__ float redr[8*32];
  __shared__ float smax[8], ssum[8];
  __shared__ float bmaxS, bsumS;
  __shared__ float hnew[32], f1o[32];
  for (int i = t; i < cnt*32; i += 512){
    int p = i >> 5, d2 = i & 31;
    curL[p*33 + d2] = cur[(size_t)(lo + p)*32 + d2];
  }
  for (int i = t; i < 96*128; i += 512){
    int j = i >> 7, o = i & 127;
    wiL[i] = (j < 64) ? wi[j*128 + o] : wh[(j-64)*128 + o];
  }
  if (t < 96) qh[t] = 0.f;
  if (t < 32) csS[t] = 0.f;
  __syncthreads();
  int wv = t >> 6, l = t & 63, d = l & 31, halfw = l >> 5;
  int p0 = wv*2 + halfw;
  for (int it = 0; it < 6; ++it){
    {
      int o = t & 127, part = t >> 7;
      const float* wp = &wiL[part*24*128 + o];
      const float* qp = &qh[part*24];
      float a = 0.f;
      #pragma unroll
      for (int jj=0;jj<24;++jj) a = fmaf(qp[jj], wp[jj*128], a);
      pbuf4[part][o] = a;
    }
    __syncthreads();
    if (t < 128) gbuf[t] = pbuf4[0][t]+pbuf4[1][t]+pbuf4[2][t]+pbuf4[3][t] + sb[t];
    __syncthreads();
    if (t < 32){
      float c = sigf(gbuf[32+t])*csS[t] + sigf(gbuf[t])*tanhf(gbuf[64+t]);
      csS[t] = c;
      qh[64+t] = sigf(gbuf[96+t])*tanhf(c);
    }
    __syncthreads();
    float lmax = -3.4e38f;
    for (int p = t; p < cnt; p += 512){
      float acc = 0.f;
      #pragma unroll
      for (int d2=0; d2<32; ++d2) acc = fmaf(curL[p*33 + d2], qh[64+d2], acc);
      ebuf[p] = acc;
      lmax = fmaxf(lmax, acc);
    }
    #pragma unroll
    for (int o2 = 1; o2 < 64; o2 <<= 1) lmax = fmaxf(lmax, __shfl_xor(lmax, o2, 64));
    if (l == 0) smax[wv] = lmax;
    __syncthreads();
    if (t == 0){ float mm = smax[0]; for (int i=1;i<8;++i) mm = fmaxf(mm, smax[i]); bmaxS = mm; }
    __syncthreads();
    float bmax = bmaxS;
    float lsum = 0.f;
    for (int p = t; p < cnt; p += 512){
      float a = expf(ebuf[p] - bmax);
      ebuf[p] = a;
      lsum += a;
    }
    #pragma unroll
    for (int o2 = 1; o2 < 64; o2 <<= 1) lsum += __shfl_xor(lsum, o2, 64);
    if (l == 0) ssum[wv] = lsum;
    __syncthreads();
    if (t == 0){ float s2 = 0.f; for (int i=0;i<8;++i) s2 += ssum[i]; bsumS = s2; }
    __syncthreads();
    float racc = 0.f;
    for (int p = p0; p < cnt; p += 16)
      racc = fmaf(ebuf[p], curL[p*33 + d], racc);
    racc += __shfl_xor(racc, 32, 64);
    if (l < 32) redr[wv*32 + l] = racc;
    __syncthreads();
    if (t < 32){
      float rsum = 0.f;
      #pragma unroll
      for (int w2=0; w2<8; ++w2) rsum += redr[w2*32 + t];
      qh[t] = qh[64+t];
      qh[32 + t] = rsum / bsumS;
    }
    __syncthreads();
  }
  if (t < 128){
    float acc = mb[t];
    for (int j=0;j<64;++j) acc = fmaf(qh[j], mwi[j*128+t], acc);
    for (int j=0;j<32;++j) acc = fmaf(hx[g*32+j], mwh[j*128+t], acc);
    gbuf[t] = acc;
  }
  __syncthreads();
  if (t < 32){
    float c = sigf(gbuf[32+t])*cx[g*32+t] + sigf(gbuf[t])*tanhf(gbuf[64+t]);
    float h = sigf(gbuf[96+t])*tanhf(c);
    out[G + g*32 + t] = h;
    out[G + G*32 + g*32 + t] = c;
    hnew[t] = h;
  }
  __syncthreads();
  if (t < 32){
    float acc = f1b[t];
    #pragma unroll
    for (int k=0;k<32;++k) acc = fmaf(hnew[k], f1w[k*32+t], acc);
    f1o[t] = fmaxf(acc, 0.f);
  }
  __syncthreads();
  if (t == 0){
    float acc = f2b[0];
    #pragma unroll
    for (int k=0;k<32;++k) acc = fmaf(f1o[k], f2w[k], acc);
    out[g] = acc;
  }
}

extern "C" void kernel_launch(void* const* d_in, const int* in_sizes, int n_in,
                              void* d_out, int out_size, void* d_ws, size_t ws_size,
                              hipStream_t stream) {
  const float* x      = (const float*)d_in[0];
  const float* ea     = (const float*)d_in[1];
  const float* hx     = (const float*)d_in[2];
  const float* cx     = (const float*)d_in[3];
  const float* lin0_w = (const float*)d_in[4];
  const float* lin0_b = (const float*)d_in[5];
  const float* e_w1   = (const float*)d_in[6];
  const float* e_b1   = (const float*)d_in[7];
  const float* e_w2   = (const float*)d_in[8];
  const float* e_b2   = (const float*)d_in[9];
  const float* root_w = (const float*)d_in[10];
  const float* conv_b = (const float*)d_in[11];
  const float* g_wih  = (const float*)d_in[12];
  const float* g_whh  = (const float*)d_in[13];
  const float* g_bih  = (const float*)d_in[14];
  const float* g_bhh  = (const float*)d_in[15];
  const float* s_wi   = (const float*)d_in[16];
  const float* s_wh   = (const float*)d_in[17];
  const float* s_b    = (const float*)d_in[18];
  const float* m_wi   = (const float*)d_in[19];
  const float* m_wh   = (const float*)d_in[20];
  const float* m_b    = (const float*)d_in[21];
  const float* f1w    = (const float*)d_in[22];
  const float* f1b    = (const float*)d_in[23];
  const float* f2w    = (const float*)d_in[24];
  const float* f2b    = (const float*)d_in[25];
  const int*   eidx   = (const int*)d_in[26];
  int N = in_sizes[0]/3;
  int E = in_sizes[1]/4;
  int G = in_sizes[2]/32;
  const int* srcI = eidx;
  const int* dstI = eidx + E;
  float* outF = (float*)d_out;

  char* wbase = (char*)d_ws; size_t off = 0;
  auto carve = [&](size_t nbytes)->char*{
    char* p = wbase + off; off = (off + nbytes + 255) & ~(size_t)255; return p;
  };
  float* cur0    = (float*)carve((size_t)N*32*4);
  float* cur1    = (float*)carve((size_t)N*32*4);
  unsigned* curq0 = (unsigned*)carve((size_t)N*32*4);
  unsigned* curq1 = (unsigned*)carve((size_t)N*32*4);
  unsigned* hidq = (unsigned*)carve((size_t)E*32*4);
  unsigned short* VrT_hi = (unsigned short*)carve((size_t)1056*32*2);
  unsigned short* VrT_lo = (unsigned short*)carve((size_t)1056*32*2);
  float* gruT    = (float*)carve((size_t)6144*4);
  float* rootT   = (float*)carve((size_t)1024*4);
  int*   counts  = (int*)carve((size_t)N*4);
  int*   cursor  = (int*)carve((size_t)N*4);
  int*   row_off = (int*)carve((size_t)(N+1)*4);
  int*   eid     = (int*)carve((size_t)E*4);
  int*   srcp    = (int*)carve((size_t)E*4);
  int*   part    = (int*)carve((size_t)256*4);
  (void)ws_size; (void)n_in; (void)out_size;

  int nch = (N + 255)/256;

  // phase A: fused pre, CSR build with parallel scan
  k_pre<<<(N*32+255)/256, 256, 0, stream>>>(x, lin0_w, lin0_b, e_w2, e_b2,
                                            g_wih, g_whh, root_w,
                                            cur0, curq0, VrT_hi, VrT_lo,
                                            gruT, rootT, counts, cursor, N);
  k_count<<<(E+255)/256, 256, 0, stream>>>(dstI, counts, E);
  k_scanA<<<nch, 256, 0, stream>>>(counts, row_off, part, N);
  k_scanB<<<1, 256, 0, stream>>>(part, row_off, nch, N);
  k_scanC<<<nch, 256, 0, stream>>>(row_off, part, N);
  k_scatter<<<(E+255)/256, 256, 0, stream>>>(dstI, row_off, cursor, eid, E);
  k_edgeCSR<<<(E*32+255)/256, 256, 0, stream>>>(eid, srcI, ea, e_w1, e_b1, hidq, srcp, E);

  // phase B: 6 fused message-passing + GRU iterations (ping-pong cur/curq)
  float* cin = cur0; float* cout = cur1;
  unsigned* qin = curq0; unsigned* qout = curq1;
  for (int it = 0; it < 6; ++it){
    k_iter<<<(N+15)/16, 512, 0, stream>>>(row_off, srcp, hidq, qin, cin,
                                          VrT_hi, VrT_lo, gruT, rootT, conv_b,
                                          g_bih, g_bhh, cout, qout, N);
    float* tf = cin; cin = cout; cout = tf;
    unsigned* tq = qin; qin = qout; qout = tq;
  }

  // phase C+D: Set2Set x6 + memory LSTM + FC head
  k_s2s<<<G, 512, 0, stream>>>(cin, s_wi, s_wh, s_b, m_wi, m_wh, m_b,
                               hx, cx, f1w, f1b, f2w, f2b, outF, N, G);
}

// Round 11
// 595.664 us; speedup vs baseline: 1.1462x; 1.1462x over previous
//
#include <hip/hip_runtime.h>
#include <math.h>

// CriticBatchNet: NNConv(+edge-net) + GRU x6, Set2Set x6, LSTM head.
// msg[e] = out[src]@W_e[e], W_e[e]=hidden[e]@e_w2+b2
//   => segsum_dst(msg)[m,f] = sum_kd S[m,kd]*Vr[kd,f],
//      S[m,k*32+d] = sum_{e:dst=m} hidden[e,k]*out[src_e,d]
//      S[m,1024+j] = sum_{e:dst=m} out[src_e,j]   (bias rows)
// v11: per-iteration k_gather (curE[p]=curq[srcp[p]], edge-parallel, no
//      barriers -> random L3 gather latency hidden by TLP); k_iter phase 1
//      now streams hidq+curE sequentially (no dependent gather chains).
//      launch_bounds back to plain 512 (v9/v10 lesson: forcing 8 waves/EU
//      caps unified VGPR+AGPR at 64 -> spill catastrophe). bf16-S LDS 38KB,
//      4-MFMA phase 2, float4 epilogue kept from v10.

typedef __attribute__((ext_vector_type(8))) short short8;
typedef __attribute__((ext_vector_type(4))) float f32x4;
typedef __attribute__((ext_vector_type(16))) float f32x16;

#define SPADU 1064   // ushort stride per S row (1056 + pad, 8-aligned)

__device__ __forceinline__ float sigf(float x){ return 1.f/(1.f+expf(-x)); }

__device__ __forceinline__ unsigned packsplit(float v){
  unsigned uv = __float_as_uint(v);
  float res = v - __uint_as_float(uv & 0xFFFF0000u);
  return (uv & 0xFFFF0000u) | (__float_as_uint(res) >> 16);
}

__device__ __forceinline__ unsigned short bf16rn(float v){
  unsigned u = __float_as_uint(v);
  return (unsigned short)((u + 0x8000u) >> 16);
}

// fused: zero counts/cursor, lin0 (f32+packed), permW2split, gruT/rootT
__global__ void k_pre(const float* __restrict__ x, const float* __restrict__ w,
                      const float* __restrict__ b,
                      const float* __restrict__ e_w2, const float* __restrict__ e_b2,
                      const float* __restrict__ g_wih, const float* __restrict__ g_whh,
                      const float* __restrict__ root_w,
                      float* __restrict__ cur, unsigned* __restrict__ curq,
                      unsigned short* __restrict__ VrT_hi,
                      unsigned short* __restrict__ VrT_lo,
                      float* __restrict__ gruT, float* __restrict__ rootT,
                      int* __restrict__ counts, int* __restrict__ cursor, int N){
  int i = blockIdx.x*blockDim.x + threadIdx.x;
  if (i < N){ counts[i]=0; cursor[i]=0; }
  if (i < N*32){
    int n = i>>5, d = i&31;
    float acc = b[d];
    acc = fmaf(x[n*3+0], w[0*32+d], acc);
    acc = fmaf(x[n*3+1], w[1*32+d], acc);
    acc = fmaf(x[n*3+2], w[2*32+d], acc);
    float v = fmaxf(acc, 0.f);
    cur[i] = v;
    curq[i] = packsplit(v);
  }
  if (i < 1056*32){
    int f = i & 31, kd = i >> 5;
    float v = (kd < 1024) ? e_w2[(kd>>5)*1024 + (kd&31)*32 + f]
                          : e_b2[(kd-1024)*32 + f];
    unsigned ub = __float_as_uint(v);
    float res = v - __uint_as_float(ub & 0xFFFF0000u);
    VrT_hi[f*1056 + kd] = (unsigned short)(ub >> 16);
    VrT_lo[f*1056 + kd] = (unsigned short)(__float_as_uint(res) >> 16);
  }
  if (i < 3072){            // gruT[0..3071] = wih^T : [(g*32+f)*32 + k]
    int fp = i >> 5, k = i & 31;
    gruT[i] = g_wih[k*96 + fp];
  } else if (i < 6144){     // gruT[3072..] = whh^T
    int j = i - 3072; int fp = j >> 5, k = j & 31;
    gruT[i] = g_whh[k*96 + fp];
  }
  if (i >= 6144 && i < 7168){ // rootT[f*32+k] = root_w[k*32+f]
    int j = i - 6144; int f = j >> 5, k = j & 31;
    rootT[j] = root_w[k*32 + f];
  }
}

__global__ void k_count(const int* __restrict__ dst, int* __restrict__ counts, int E){
  int i = blockIdx.x*blockDim.x + threadIdx.x;
  if (i < E) atomicAdd(&counts[dst[i]], 1);
}

// 3-stage parallel exclusive scan
__global__ void k_scanA(const int* __restrict__ counts, int* __restrict__ row_off,
                        int* __restrict__ part, int N){
  __shared__ int buf[256];
  int b = blockIdx.x, t = threadIdx.x, base = b*256;
  int v = (base + t < N) ? counts[base + t] : 0;
  buf[t] = v; __syncthreads();
  #pragma unroll
  for (int off = 1; off < 256; off <<= 1){
    int tmp = (t >= off) ? buf[t-off] : 0;
    __syncthreads();
    buf[t] += tmp;
    __syncthreads();
  }
  if (base + t < N) row_off[base + t] = buf[t] - v;
  if (t == 255) part[b] = buf[255];
}

__global__ void k_scanB(int* __restrict__ part, int* __restrict__ row_off,
                        int nch, int N){
  __shared__ int buf[256];
  int t = threadIdx.x;
  int v = (t < nch) ? part[t] : 0;
  buf[t] = v; __syncthreads();
  #pragma unroll
  for (int off = 1; off < 256; off <<= 1){
    int tmp = (t >= off) ? buf[t-off] : 0;
    __syncthreads();
    buf[t] += tmp;
    __syncthreads();
  }
  if (t < nch) part[t] = buf[t] - v;
  if (t == 255) row_off[N] = buf[255];
}

__global__ void k_scanC(int* __restrict__ row_off, const int* __restrict__ part, int N){
  int i = blockIdx.x*256 + threadIdx.x;
  if (i < N) row_off[i] += part[blockIdx.x];
}

__global__ void k_scatter(const int* __restrict__ dst, const int* __restrict__ row_off,
                          int* __restrict__ cursor, int* __restrict__ eid, int E){
  int i = blockIdx.x*blockDim.x + threadIdx.x;
  if (i < E){
    int dn = dst[i];
    int pos = row_off[dn] + atomicAdd(&cursor[dn], 1);
    eid[pos] = i;
  }
}

// fused: hidq[p] = packsplit(relu(ea[eid[p]] @ e_w1 + e_b1)), srcp[p] = src[eid[p]]
__global__ void k_edgeCSR(const int* __restrict__ eid, const int* __restrict__ src,
                          const float* __restrict__ ea, const float* __restrict__ w,
                          const float* __restrict__ b, unsigned* __restrict__ hidq,
                          int* __restrict__ srcp, int E){
  int i = blockIdx.x*blockDim.x + threadIdx.x;
  if (i >= E*32) return;
  int p = i>>5, d = i&31;
  int e = eid[p];
  const float4* ea4 = (const float4*)ea;
  float4 v = ea4[e];
  float acc = b[d];
  acc = fmaf(v.x, w[0*32+d], acc);
  acc = fmaf(v.y, w[1*32+d], acc);
  acc = fmaf(v.z, w[2*32+d], acc);
  acc = fmaf(v.w, w[3*32+d], acc);
  hidq[i] = packsplit(fmaxf(acc, 0.f));
  if (d == 0) srcp[p] = src[e];
}

// Edge-parallel gather: curE[p*32+c] = curq[srcp[p]*32+c]. No barriers,
// massive TLP -> random L3 latency fully hidden. Grid-stride.
__global__ __launch_bounds__(256) void k_gather(
    const int* __restrict__ srcp, const unsigned* __restrict__ curq,
    unsigned* __restrict__ curE, int E32){
  int stride = gridDim.x*256;
  for (int i = blockIdx.x*256 + threadIdx.x; i < E32; i += stride){
    int p = i >> 5, c = i & 31;
    curE[i] = curq[srcp[p]*32 + c];
  }
}

// Fused per-iteration kernel: 512 threads, 8 waves, 16 nodes (2/wave seq).
// Phase 1 streams hidq+curE sequentially (gather pre-hoisted).
__global__ __launch_bounds__(512) void k_iter(
    const int* __restrict__ row_off,
    const unsigned* __restrict__ hidq, const unsigned* __restrict__ curE,
    const float* __restrict__ cur_in,
    const unsigned short* __restrict__ VrT_hi, const unsigned short* __restrict__ VrT_lo,
    const float* __restrict__ gruT, const float* __restrict__ rootT,
    const float* __restrict__ conv_b,
    const float* __restrict__ bih, const float* __restrict__ bhh,
    float* __restrict__ cur_out, unsigned* __restrict__ curq_out, int N){
  __shared__ __align__(16) unsigned short s_hi[16*SPADU]; // bf16 S rows (34KB)
  __shared__ float htile[16*32];
  __shared__ float mtile[16*32];
  int nb = blockIdx.x*16;
  int t = threadIdx.x;
  int w = t >> 6, l = t & 63, col = l & 31, half = l >> 5;

  // stage htile early — overlaps phase 1
  {
    int node = t >> 5, f = t & 31;
    int n2 = nb + node;
    htile[t] = (n2 < N) ? cur_in[n2*32 + f] : 0.f;
  }

  // ---- phase 1: 2 nodes per wave (sequential), MFMA outer products ----
  #pragma unroll
  for (int q = 0; q < 2; ++q){
    int n = nb + 2*w + q;
    f32x16 S = {0.f,0.f,0.f,0.f,0.f,0.f,0.f,0.f,0.f,0.f,0.f,0.f,0.f,0.f,0.f,0.f};
    float aex = 0.f;
    int lo = 0, hi = 0;
    if (n < N){ lo = row_off[n]; hi = row_off[n+1]; }
    for (int p0 = lo; p0 < hi; p0 += 16){
      short8 Ah, Al, Bh, Bl;
      #pragma unroll
      for (int j=0;j<8;++j){
        int pp = p0 + 8*half + j;
        bool val = pp < hi;
        int idx = val ? pp : 0;
        unsigned hp = hidq[idx*32 + col];   // sequential stream
        unsigned o  = curE[idx*32 + col];   // sequential stream (pre-gathered)
        hp = val ? hp : 0u;
        o  = val ? o  : 0u;
        Ah[j] = (short)(hp >> 16);
        Al[j] = (short)(hp & 0xffffu);
        Bh[j] = (short)(o >> 16);
        Bl[j] = (short)(o & 0xffffu);
        aex += __uint_as_float(o & 0xFFFF0000u) + __uint_as_float(o << 16);
      }
      S = __builtin_amdgcn_mfma_f32_32x32x16_bf16(Ah, Bh, S, 0,0,0);
      S = __builtin_amdgcn_mfma_f32_32x32x16_bf16(Al, Bh, S, 0,0,0);
      S = __builtin_amdgcn_mfma_f32_32x32x16_bf16(Ah, Bl, S, 0,0,0);
    }
    // write bf16 S row: C layout row k=(i&3)+8*(i>>2)+4*half, col=d
    unsigned short* sp = &s_hi[(2*w+q)*SPADU];
    #pragma unroll
    for (int i=0;i<16;++i){
      int k = (i&3) + 8*(i>>2) + 4*half;
      sp[k*32 + col] = bf16rn(S[i]);
    }
    aex += __shfl_xor(aex, 32, 64);
    if (l < 32) sp[1024 + l] = bf16rn(aex);
  }
  __syncthreads();

  // ---- phase 2: C[m][f] = sum_kd S[m][kd]*Vr[kd][f], 33 K-steps / 8 waves ----
  int fc = l & 15, hq = l >> 4;
  {
    const unsigned short* arow = &s_hi[fc*SPADU];
    const unsigned short* bh0p = VrT_hi + fc*1056;
    const unsigned short* bl0p = VrT_lo + fc*1056;
    const unsigned short* bh1p = VrT_hi + (16+fc)*1056;
    const unsigned short* bl1p = VrT_lo + (16+fc)*1056;
    f32x4 acc0 = {0.f,0.f,0.f,0.f}, acc1 = {0.f,0.f,0.f,0.f};
    int s_lo = (w*33) >> 3, s_hiS = ((w+1)*33) >> 3;
    for (int st = s_lo; st < s_hiS; ++st){
      int kb = st*32 + hq*8;
      short8 Ah  = *(const short8*)(arow + kb);     // direct bf16 A fragment
      short8 bh0 = *(const short8*)(bh0p + kb);
      short8 bl0 = *(const short8*)(bl0p + kb);
      short8 bh1 = *(const short8*)(bh1p + kb);
      short8 bl1 = *(const short8*)(bl1p + kb);
      acc0 = __builtin_amdgcn_mfma_f32_16x16x32_bf16(Ah, bh0, acc0, 0,0,0);
      acc0 = __builtin_amdgcn_mfma_f32_16x16x32_bf16(Ah, bl0, acc0, 0,0,0);
      acc1 = __builtin_amdgcn_mfma_f32_16x16x32_bf16(Ah, bh1, acc1, 0,0,0);
      acc1 = __builtin_amdgcn_mfma_f32_16x16x32_bf16(Ah, bl1, acc1, 0,0,0);
    }
    __syncthreads();                     // all s_hi reads done
    float* pbuf = (float*)s_hi;          // reuse: [w][m(16)][32] = 16KB
    #pragma unroll
    for (int i=0;i<4;++i){
      int m = hq*4 + i;
      pbuf[(w*16 + m)*32 + fc]      = acc0[i];
      pbuf[(w*16 + m)*32 + 16 + fc] = acc1[i];
    }
  }
  __syncthreads();

  // ---- epilogue: reduce partials, root+relu -> m, then GRU ----
  int node = t >> 5, f = t & 31;
  int n2 = nb + node;
  const float* pbuf = (const float*)s_hi;
  if (n2 < N){
    float msum = 0.f;
    #pragma unroll
    for (int w2=0; w2<8; ++w2) msum += pbuf[(w2*16 + node)*32 + f];
    float deg = (float)max(row_off[n2+1] - row_off[n2], 1);
    float rt = 0.f;
    const float4* rT4 = (const float4*)(rootT + f*32);
    const float4* h4  = (const float4*)(htile + node*32);
    #pragma unroll
    for (int k4=0;k4<8;++k4){
      float4 wv = rT4[k4]; float4 hv = h4[k4];
      rt = fmaf(hv.x, wv.x, rt); rt = fmaf(hv.y, wv.y, rt);
      rt = fmaf(hv.z, wv.z, rt); rt = fmaf(hv.w, wv.w, rt);
    }
    mtile[node*32 + f] = fmaxf(msum/deg + rt + conv_b[f], 0.f);
  }
  __syncthreads();
  if (n2 < N){
    float gr = bih[f], gz = bih[32+f], gn = bih[64+f];
    float hr = bhh[f], hz = bhh[32+f], hn = bhh[64+f];
    const float4* m4 = (const float4*)(mtile + node*32);
    const float4* h4 = (const float4*)(htile + node*32);
    const float4* w0 = (const float4*)(gruT + (0*32+f)*32);
    const float4* w1 = (const float4*)(gruT + (1*32+f)*32);
    const float4* w2 = (const float4*)(gruT + (2*32+f)*32);
    const float4* u0 = (const float4*)(gruT + 3072 + (0*32+f)*32);
    const float4* u1 = (const float4*)(gruT + 3072 + (1*32+f)*32);
    const float4* u2 = (const float4*)(gruT + 3072 + (2*32+f)*32);
    #pragma unroll
    for (int k4=0;k4<8;++k4){
      float4 mv = m4[k4], hv = h4[k4];
      float4 a0 = w0[k4], a1 = w1[k4], a2 = w2[k4];
      float4 b0 = u0[k4], b1 = u1[k4], b2 = u2[k4];
      gr = fmaf(mv.x,a0.x,gr); gr = fmaf(mv.y,a0.y,gr); gr = fmaf(mv.z,a0.z,gr); gr = fmaf(mv.w,a0.w,gr);
      gz = fmaf(mv.x,a1.x,gz); gz = fmaf(mv.y,a1.y,gz); gz = fmaf(mv.z,a1.z,gz); gz = fmaf(mv.w,a1.w,gz);
      gn = fmaf(mv.x,a2.x,gn); gn = fmaf(mv.y,a2.y,gn); gn = fmaf(mv.z,a2.z,gn); gn = fmaf(mv.w,a2.w,gn);
      hr = fmaf(hv.x,b0.x,hr); hr = fmaf(hv.y,b0.y,hr); hr = fmaf(hv.z,b0.z,hr); hr = fmaf(hv.w,b0.w,hr);
      hz = fmaf(hv.x,b1.x,hz); hz = fmaf(hv.y,b1.y,hz); hz = fmaf(hv.z,b1.z,hz); hz = fmaf(hv.w,b1.w,hz);
      hn = fmaf(hv.x,b2.x,hn); hn = fmaf(hv.y,b2.y,hn); hn = fmaf(hv.z,b2.z,hn); hn = fmaf(hv.w,b2.w,hn);
    }
    float r = sigf(gr + hr);
    float z = sigf(gz + hz);
    float nn2 = tanhf(gn + r*hn);
    float hcur = htile[node*32 + f];
    float nv = (1.f - z)*nn2 + z*hcur;
    cur_out[n2*32 + f] = nv;
    curq_out[n2*32 + f] = packsplit(nv);
  }
}

// Set2Set x6 + memory LSTM + FC head; one 512-thread block per graph.
#define S2S_CAP 480
__global__ __launch_bounds__(512) void k_s2s(
    const float* __restrict__ cur,
    const float* __restrict__ wi, const float* __restrict__ wh, const float* __restrict__ sb,
    const float* __restrict__ mwi, const float* __restrict__ mwh, const float* __restrict__ mb,
    const float* __restrict__ hx, const float* __restrict__ cx,
    const float* __restrict__ f1w, const float* __restrict__ f1b,
    const float* __restrict__ f2w, const float* __restrict__ f2b,
    float* __restrict__ out, int N, int G){
  int g = blockIdx.x, t = threadIdx.x;
  int lo = (int)(((long long)g*N + G - 1)/G);
  int hi = (int)(((long long)(g+1)*N + G - 1)/G);
  int cnt = hi - lo;
  __shared__ float curL[S2S_CAP*33];
  __shared__ float wiL[96*128];
  __shared__ float ebuf[S2S_CAP];
  __shared__ float qh[96];
  __shared__ float csS[32];
  __shared__ float gbuf[128];
  __shared__ float pbuf4[4][128];
  __shared__ float redr[8*32];
  __shared__ float smax[8], ssum[8];
  __shared__ float bmaxS, bsumS;
  __shared__ float hnew[32], f1o[32];
  for (int i = t; i < cnt*32; i += 512){
    int p = i >> 5, d2 = i & 31;
    curL[p*33 + d2] = cur[(size_t)(lo + p)*32 + d2];
  }
  for (int i = t; i < 96*128; i += 512){
    int j = i >> 7, o = i & 127;
    wiL[i] = (j < 64) ? wi[j*128 + o] : wh[(j-64)*128 + o];
  }
  if (t < 96) qh[t] = 0.f;
  if (t < 32) csS[t] = 0.f;
  __syncthreads();
  int wv = t >> 6, l = t & 63, d = l & 31, halfw = l >> 5;
  int p0 = wv*2 + halfw;
  for (int it = 0; it < 6; ++it){
    {
      int o = t & 127, part = t >> 7;
      const float* wp = &wiL[part*24*128 + o];
      const float* qp = &qh[part*24];
      float a = 0.f;
      #pragma unroll
      for (int jj=0;jj<24;++jj) a = fmaf(qp[jj], wp[jj*128], a);
      pbuf4[part][o] = a;
    }
    __syncthreads();
    if (t < 128) gbuf[t] = pbuf4[0][t]+pbuf4[1][t]+pbuf4[2][t]+pbuf4[3][t] + sb[t];
    __syncthreads();
    if (t < 32){
      float c = sigf(gbuf[32+t])*csS[t] + sigf(gbuf[t])*tanhf(gbuf[64+t]);
      csS[t] = c;
      qh[64+t] = sigf(gbuf[96+t])*tanhf(c);
    }
    __syncthreads();
    float lmax = -3.4e38f;
    for (int p = t; p < cnt; p += 512){
      float acc = 0.f;
      #pragma unroll
      for (int d2=0; d2<32; ++d2) acc = fmaf(curL[p*33 + d2], qh[64+d2], acc);
      ebuf[p] = acc;
      lmax = fmaxf(lmax, acc);
    }
    #pragma unroll
    for (int o2 = 1; o2 < 64; o2 <<= 1) lmax = fmaxf(lmax, __shfl_xor(lmax, o2, 64));
    if (l == 0) smax[wv] = lmax;
    __syncthreads();
    if (t == 0){ float mm = smax[0]; for (int i=1;i<8;++i) mm = fmaxf(mm, smax[i]); bmaxS = mm; }
    __syncthreads();
    float bmax = bmaxS;
    float lsum = 0.f;
    for (int p = t; p < cnt; p += 512){
      float a = expf(ebuf[p] - bmax);
      ebuf[p] = a;
      lsum += a;
    }
    #pragma unroll
    for (int o2 = 1; o2 < 64; o2 <<= 1) lsum += __shfl_xor(lsum, o2, 64);
    if (l == 0) ssum[wv] = lsum;
    __syncthreads();
    if (t == 0){ float s2 = 0.f; for (int i=0;i<8;++i) s2 += ssum[i]; bsumS = s2; }
    __syncthreads();
    float racc = 0.f;
    for (int p = p0; p < cnt; p += 16)
      racc = fmaf(ebuf[p], curL[p*33 + d], racc);
    racc += __shfl_xor(racc, 32, 64);
    if (l < 32) redr[wv*32 + l] = racc;
    __syncthreads();
    if (t < 32){
      float rsum = 0.f;
      #pragma unroll
      for (int w2=0; w2<8; ++w2) rsum += redr[w2*32 + t];
      qh[t] = qh[64+t];
      qh[32 + t] = rsum / bsumS;
    }
    __syncthreads();
  }
  if (t < 128){
    float acc = mb[t];
    for (int j=0;j<64;++j) acc = fmaf(qh[j], mwi[j*128+t], acc);
    for (int j=0;j<32;++j) acc = fmaf(hx[g*32+j], mwh[j*128+t], acc);
    gbuf[t] = acc;
  }
  __syncthreads();
  if (t < 32){
    float c = sigf(gbuf[32+t])*cx[g*32+t] + sigf(gbuf[t])*tanhf(gbuf[64+t]);
    float h = sigf(gbuf[96+t])*tanhf(c);
    out[G + g*32 + t] = h;
    out[G + G*32 + g*32 + t] = c;
    hnew[t] = h;
  }
  __syncthreads();
  if (t < 32){
    float acc = f1b[t];
    #pragma unroll
    for (int k=0;k<32;++k) acc = fmaf(hnew[k], f1w[k*32+t], acc);
    f1o[t] = fmaxf(acc, 0.f);
  }
  __syncthreads();
  if (t == 0){
    float acc = f2b[0];
    #pragma unroll
    for (int k=0;k<32;++k) acc = fmaf(f1o[k], f2w[k], acc);
    out[g] = acc;
  }
}

extern "C" void kernel_launch(void* const* d_in, const int* in_sizes, int n_in,
                              void* d_out, int out_size, void* d_ws, size_t ws_size,
                              hipStream_t stream) {
  const float* x      = (const float*)d_in[0];
  const float* ea     = (const float*)d_in[1];
  const float* hx     = (const float*)d_in[2];
  const float* cx     = (const float*)d_in[3];
  const float* lin0_w = (const float*)d_in[4];
  const float* lin0_b = (const float*)d_in[5];
  const float* e_w1   = (const float*)d_in[6];
  const float* e_b1   = (const float*)d_in[7];
  const float* e_w2   = (const float*)d_in[8];
  const float* e_b2   = (const float*)d_in[9];
  const float* root_w = (const float*)d_in[10];
  const float* conv_b = (const float*)d_in[11];
  const float* g_wih  = (const float*)d_in[12];
  const float* g_whh  = (const float*)d_in[13];
  const float* g_bih  = (const float*)d_in[14];
  const float* g_bhh  = (const float*)d_in[15];
  const float* s_wi   = (const float*)d_in[16];
  const float* s_wh   = (const float*)d_in[17];
  const float* s_b    = (const float*)d_in[18];
  const float* m_wi   = (const float*)d_in[19];
  const float* m_wh   = (const float*)d_in[20];
  const float* m_b    = (const float*)d_in[21];
  const float* f1w    = (const float*)d_in[22];
  const float* f1b    = (const float*)d_in[23];
  const float* f2w    = (const float*)d_in[24];
  const float* f2b    = (const float*)d_in[25];
  const int*   eidx   = (const int*)d_in[26];
  int N = in_sizes[0]/3;
  int E = in_sizes[1]/4;
  int G = in_sizes[2]/32;
  const int* srcI = eidx;
  const int* dstI = eidx + E;
  float* outF = (float*)d_out;

  char* wbase = (char*)d_ws; size_t off = 0;
  auto carve = [&](size_t nbytes)->char*{
    char* p = wbase + off; off = (off + nbytes + 255) & ~(size_t)255; return p;
  };
  float* cur0    = (float*)carve((size_t)N*32*4);
  float* cur1    = (float*)carve((size_t)N*32*4);
  unsigned* curq0 = (unsigned*)carve((size_t)N*32*4);
  unsigned* curq1 = (unsigned*)carve((size_t)N*32*4);
  unsigned* hidq = (unsigned*)carve((size_t)E*32*4);
  unsigned* curE = (unsigned*)carve((size_t)E*32*4);
  unsigned short* VrT_hi = (unsigned short*)carve((size_t)1056*32*2);
  unsigned short* VrT_lo = (unsigned short*)carve((size_t)1056*32*2);
  float* gruT    = (float*)carve((size_t)6144*4);
  float* rootT   = (float*)carve((size_t)1024*4);
  int*   counts  = (int*)carve((size_t)N*4);
  int*   cursor  = (int*)carve((size_t)N*4);
  int*   row_off = (int*)carve((size_t)(N+1)*4);
  int*   eid     = (int*)carve((size_t)E*4);
  int*   srcp    = (int*)carve((size_t)E*4);
  int*   part    = (int*)carve((size_t)256*4);
  (void)ws_size; (void)n_in; (void)out_size;

  int nch = (N + 255)/256;

  // phase A: fused pre, CSR build with parallel scan
  k_pre<<<(N*32+255)/256, 256, 0, stream>>>(x, lin0_w, lin0_b, e_w2, e_b2,
                                            g_wih, g_whh, root_w,
                                            cur0, curq0, VrT_hi, VrT_lo,
                                            gruT, rootT, counts, cursor, N);
  k_count<<<(E+255)/256, 256, 0, stream>>>(dstI, counts, E);
  k_scanA<<<nch, 256, 0, stream>>>(counts, row_off, part, N);
  k_scanB<<<1, 256, 0, stream>>>(part, row_off, nch, N);
  k_scanC<<<nch, 256, 0, stream>>>(row_off, part, N);
  k_scatter<<<(E+255)/256, 256, 0, stream>>>(dstI, row_off, cursor, eid, E);
  k_edgeCSR<<<(E*32+255)/256, 256, 0, stream>>>(eid, srcI, ea, e_w1, e_b1, hidq, srcp, E);

  // phase B: 6 x (gather + fused iter), ping-pong cur/curq
  float* cin = cur0; float* cout = cur1;
  unsigned* qin = curq0; unsigned* qout = curq1;
  for (int it = 0; it < 6; ++it){
    k_gather<<<4096, 256, 0, stream>>>(srcp, qin, curE, E*32);
    k_iter<<<(N+15)/16, 512, 0, stream>>>(row_off, hidq, curE, cin,
                                          VrT_hi, VrT_lo, gruT, rootT, conv_b,
                                          g_bih, g_bhh, cout, qout, N);
    float* tf = cin; cin = cout; cout = tf;
    unsigned* tq = qin; qin = qout; qout = tq;
  }

  // phase C+D: Set2Set x6 + memory LSTM + FC head
  k_s2s<<<G, 512, 0, stream>>>(cin, s_wi, s_wh, s_b, m_wi, m_wh, m_b,
                               hx, cx, f1w, f1b, f2w, f2b, outF, N, G);
}

// Round 12
// 521.536 us; speedup vs baseline: 1.3091x; 1.1421x over previous
//
#include <hip/hip_runtime.h>
#include <math.h>

// CriticBatchNet: NNConv(+edge-net) + GRU x6, Set2Set x6, LSTM head.
// msg[e] = out[src]@W_e[e], W_e[e]=hidden[e]@e_w2+b2
//   => segsum_dst(msg)[m,f] = sum_kd S[m,kd]*Vr[kd,f],
//      S[m,k*32+d] = sum_{e:dst=m} hidden[e,k]*out[src_e,d]
//      S[m,1024+j] = sum_{e:dst=m} out[src_e,j]   (bias rows)
// v12 = v8 skeleton (dual-node fast path, in-kernel packed gather — the
//       proven 44.5us structure) + bf16-S plane (LDS 38KB), 4-MFMA phase 2
//       with direct short8 A read + B prefetch, float4 gruT/rootT epilogue.
//       No launch-bounds forcing (v9-v11 lesson: VGPR<=64 always spills;
//       16 waves/CU is the real tier).

typedef __attribute__((ext_vector_type(8))) short short8;
typedef __attribute__((ext_vector_type(4))) float f32x4;
typedef __attribute__((ext_vector_type(16))) float f32x16;

#define SPADU 1064   // ushort stride per S row (1056 + pad, 8-aligned)

__device__ __forceinline__ float sigf(float x){ return 1.f/(1.f+expf(-x)); }

__device__ __forceinline__ unsigned packsplit(float v){
  unsigned uv = __float_as_uint(v);
  float res = v - __uint_as_float(uv & 0xFFFF0000u);
  return (uv & 0xFFFF0000u) | (__float_as_uint(res) >> 16);
}

__device__ __forceinline__ unsigned short bf16rn(float v){
  unsigned u = __float_as_uint(v);
  return (unsigned short)((u + 0x8000u) >> 16);
}

__device__ __forceinline__ short8 ld8(const unsigned short* p){
  return *(const short8*)p;
}

// fused: zero counts/cursor, lin0 (f32+packed), permW2split, gruT/rootT
__global__ void k_pre(const float* __restrict__ x, const float* __restrict__ w,
                      const float* __restrict__ b,
                      const float* __restrict__ e_w2, const float* __restrict__ e_b2,
                      const float* __restrict__ g_wih, const float* __restrict__ g_whh,
                      const float* __restrict__ root_w,
                      float* __restrict__ cur, unsigned* __restrict__ curq,
                      unsigned short* __restrict__ VrT_hi,
                      unsigned short* __restrict__ VrT_lo,
                      float* __restrict__ gruT, float* __restrict__ rootT,
                      int* __restrict__ counts, int* __restrict__ cursor, int N){
  int i = blockIdx.x*blockDim.x + threadIdx.x;
  if (i < N){ counts[i]=0; cursor[i]=0; }
  if (i < N*32){
    int n = i>>5, d = i&31;
    float acc = b[d];
    acc = fmaf(x[n*3+0], w[0*32+d], acc);
    acc = fmaf(x[n*3+1], w[1*32+d], acc);
    acc = fmaf(x[n*3+2], w[2*32+d], acc);
    float v = fmaxf(acc, 0.f);
    cur[i] = v;
    curq[i] = packsplit(v);
  }
  if (i < 1056*32){
    int f = i & 31, kd = i >> 5;
    float v = (kd < 1024) ? e_w2[(kd>>5)*1024 + (kd&31)*32 + f]
                          : e_b2[(kd-1024)*32 + f];
    unsigned ub = __float_as_uint(v);
    float res = v - __uint_as_float(ub & 0xFFFF0000u);
    VrT_hi[f*1056 + kd] = (unsigned short)(ub >> 16);
    VrT_lo[f*1056 + kd] = (unsigned short)(__float_as_uint(res) >> 16);
  }
  if (i < 3072){            // gruT[0..3071] = wih^T : [(g*32+f)*32 + k]
    int fp = i >> 5, k = i & 31;
    gruT[i] = g_wih[k*96 + fp];
  } else if (i < 6144){     // gruT[3072..] = whh^T
    int j = i - 3072; int fp = j >> 5, k = j & 31;
    gruT[i] = g_whh[k*96 + fp];
  }
  if (i >= 6144 && i < 7168){ // rootT[f*32+k] = root_w[k*32+f]
    int j = i - 6144; int f = j >> 5, k = j & 31;
    rootT[j] = root_w[k*32 + f];
  }
}

__global__ void k_count(const int* __restrict__ dst, int* __restrict__ counts, int E){
  int i = blockIdx.x*blockDim.x + threadIdx.x;
  if (i < E) atomicAdd(&counts[dst[i]], 1);
}

// 3-stage parallel exclusive scan
__global__ void k_scanA(const int* __restrict__ counts, int* __restrict__ row_off,
                        int* __restrict__ part, int N){
  __shared__ int buf[256];
  int b = blockIdx.x, t = threadIdx.x, base = b*256;
  int v = (base + t < N) ? counts[base + t] : 0;
  buf[t] = v; __syncthreads();
  #pragma unroll
  for (int off = 1; off < 256; off <<= 1){
    int tmp = (t >= off) ? buf[t-off] : 0;
    __syncthreads();
    buf[t] += tmp;
    __syncthreads();
  }
  if (base + t < N) row_off[base + t] = buf[t] - v;
  if (t == 255) part[b] = buf[255];
}

__global__ void k_scanB(int* __restrict__ part, int* __restrict__ row_off,
                        int nch, int N){
  __shared__ int buf[256];
  int t = threadIdx.x;
  int v = (t < nch) ? part[t] : 0;
  buf[t] = v; __syncthreads();
  #pragma unroll
  for (int off = 1; off < 256; off <<= 1){
    int tmp = (t >= off) ? buf[t-off] : 0;
    __syncthreads();
    buf[t] += tmp;
    __syncthreads();
  }
  if (t < nch) part[t] = buf[t] - v;
  if (t == 255) row_off[N] = buf[255];
}

__global__ void k_scanC(int* __restrict__ row_off, const int* __restrict__ part, int N){
  int i = blockIdx.x*256 + threadIdx.x;
  if (i < N) row_off[i] += part[blockIdx.x];
}

__global__ void k_scatter(const int* __restrict__ dst, const int* __restrict__ row_off,
                          int* __restrict__ cursor, int* __restrict__ eid, int E){
  int i = blockIdx.x*blockDim.x + threadIdx.x;
  if (i < E){
    int dn = dst[i];
    int pos = row_off[dn] + atomicAdd(&cursor[dn], 1);
    eid[pos] = i;
  }
}

// fused: hidq[p] = packsplit(relu(ea[eid[p]] @ e_w1 + e_b1)), srcp[p] = src[eid[p]]
__global__ void k_edgeCSR(const int* __restrict__ eid, const int* __restrict__ src,
                          const float* __restrict__ ea, const float* __restrict__ w,
                          const float* __restrict__ b, unsigned* __restrict__ hidq,
                          int* __restrict__ srcp, int E){
  int i = blockIdx.x*blockDim.x + threadIdx.x;
  if (i >= E*32) return;
  int p = i>>5, d = i&31;
  int e = eid[p];
  const float4* ea4 = (const float4*)ea;
  float4 v = ea4[e];
  float acc = b[d];
  acc = fmaf(v.x, w[0*32+d], acc);
  acc = fmaf(v.y, w[1*32+d], acc);
  acc = fmaf(v.z, w[2*32+d], acc);
  acc = fmaf(v.w, w[3*32+d], acc);
  hidq[i] = packsplit(fmaxf(acc, 0.f));
  if (d == 0) srcp[p] = src[e];
}

// Fused per-iteration kernel: 512 threads, 8 waves, 16 nodes (2/wave).
__global__ __launch_bounds__(512) void k_iter(
    const int* __restrict__ row_off, const int* __restrict__ srcp,
    const unsigned* __restrict__ hidq, const unsigned* __restrict__ curq_in,
    const float* __restrict__ cur_in,
    const unsigned short* __restrict__ VrT_hi, const unsigned short* __restrict__ VrT_lo,
    const float* __restrict__ gruT, const float* __restrict__ rootT,
    const float* __restrict__ conv_b,
    const float* __restrict__ bih, const float* __restrict__ bhh,
    float* __restrict__ cur_out, unsigned* __restrict__ curq_out, int N){
  __shared__ __align__(16) unsigned short s_hi[16*SPADU]; // bf16 S rows (34KB)
  __shared__ float htile[16*32];
  __shared__ float mtile[16*32];
  int nb = blockIdx.x*16;
  int t = threadIdx.x;
  int w = t >> 6, l = t & 63, col = l & 31, half = l >> 5;

  // stage htile early — overlaps phase 1
  {
    int node = t >> 5, f = t & 31;
    int n2 = nb + node;
    htile[t] = (n2 < N) ? cur_in[n2*32 + f] : 0.f;
  }

  // ---- phase 1: 2 nodes per wave, dual-node fused fast path ----
  int nA = nb + 2*w;
  int loA = row_off[min(nA, N)],   hiA = row_off[min(nA+1, N)];
  int loB = row_off[min(nA+1, N)], hiB = row_off[min(nA+2, N)];
  int degA = hiA - loA, degB = hiB - loB;
  f32x16 SA = {0.f,0.f,0.f,0.f,0.f,0.f,0.f,0.f,0.f,0.f,0.f,0.f,0.f,0.f,0.f,0.f};
  f32x16 SB = SA;
  float aexA = 0.f, aexB = 0.f;

  if (degA <= 16 && degB <= 16){
    // FAST PATH (>99% of waves): both nodes' load streams in flight together.
    unsigned rh[2][8], ro[2][8];
    #pragma unroll
    for (int j=0;j<8;++j){
      int pA = loA + 8*half + j; bool vA = pA < hiA; int iA = vA ? pA : 0;
      int pB = loB + 8*half + j; bool vB = pB < hiB; int iB = vB ? pB : 0;
      unsigned hA = hidq[iA*32 + col];
      unsigned hB = hidq[iB*32 + col];
      unsigned oA = curq_in[srcp[iA]*32 + col];
      unsigned oB = curq_in[srcp[iB]*32 + col];
      rh[0][j] = vA ? hA : 0u;  ro[0][j] = vA ? oA : 0u;
      rh[1][j] = vB ? hB : 0u;  ro[1][j] = vB ? oB : 0u;
    }
    {
      short8 Ah, Al, Bh, Bl;
      #pragma unroll
      for (int j=0;j<8;++j){
        unsigned h = rh[0][j], o = ro[0][j];
        Ah[j]=(short)(h>>16); Al[j]=(short)(h&0xffffu);
        Bh[j]=(short)(o>>16); Bl[j]=(short)(o&0xffffu);
        aexA += __uint_as_float(o & 0xFFFF0000u) + __uint_as_float(o << 16);
      }
      SA = __builtin_amdgcn_mfma_f32_32x32x16_bf16(Ah, Bh, SA, 0,0,0);
      SA = __builtin_amdgcn_mfma_f32_32x32x16_bf16(Al, Bh, SA, 0,0,0);
      SA = __builtin_amdgcn_mfma_f32_32x32x16_bf16(Ah, Bl, SA, 0,0,0);
    }
    {
      short8 Ah, Al, Bh, Bl;
      #pragma unroll
      for (int j=0;j<8;++j){
        unsigned h = rh[1][j], o = ro[1][j];
        Ah[j]=(short)(h>>16); Al[j]=(short)(h&0xffffu);
        Bh[j]=(short)(o>>16); Bl[j]=(short)(o&0xffffu);
        aexB += __uint_as_float(o & 0xFFFF0000u) + __uint_as_float(o << 16);
      }
      SB = __builtin_amdgcn_mfma_f32_32x32x16_bf16(Ah, Bh, SB, 0,0,0);
      SB = __builtin_amdgcn_mfma_f32_32x32x16_bf16(Al, Bh, SB, 0,0,0);
      SB = __builtin_amdgcn_mfma_f32_32x32x16_bf16(Ah, Bl, SB, 0,0,0);
    }
  } else {
    // SLOW PATH (high-degree): per-node chunk loop
    #pragma unroll
    for (int q = 0; q < 2; ++q){
      int lo2 = q ? loB : loA, hi2 = q ? hiB : hiA;
      f32x16 Sc = {0.f,0.f,0.f,0.f,0.f,0.f,0.f,0.f,0.f,0.f,0.f,0.f,0.f,0.f,0.f,0.f};
      float aex = 0.f;
      for (int p0 = lo2; p0 < hi2; p0 += 16){
        short8 Ah, Al, Bh, Bl;
        #pragma unroll
        for (int j=0;j<8;++j){
          int pp = p0 + 8*half + j;
          bool val = pp < hi2;
          int idx = val ? pp : 0;
          unsigned hp = hidq[idx*32 + col];
          unsigned o  = curq_in[srcp[idx]*32 + col];
          hp = val ? hp : 0u;
          o  = val ? o  : 0u;
          Ah[j] = (short)(hp >> 16);
          Al[j] = (short)(hp & 0xffffu);
          Bh[j] = (short)(o >> 16);
          Bl[j] = (short)(o & 0xffffu);
          aex += __uint_as_float(o & 0xFFFF0000u) + __uint_as_float(o << 16);
        }
        Sc = __builtin_amdgcn_mfma_f32_32x32x16_bf16(Ah, Bh, Sc, 0,0,0);
        Sc = __builtin_amdgcn_mfma_f32_32x32x16_bf16(Al, Bh, Sc, 0,0,0);
        Sc = __builtin_amdgcn_mfma_f32_32x32x16_bf16(Ah, Bl, Sc, 0,0,0);
      }
      if (q == 0){ SA = Sc; aexA = aex; } else { SB = Sc; aexB = aex; }
    }
  }
  // write bf16 S rows: C layout row k=(i&3)+8*(i>>2)+4*half, col=d
  {
    unsigned short* sp = &s_hi[(2*w)*SPADU];
    #pragma unroll
    for (int i=0;i<16;++i){
      int k = (i&3) + 8*(i>>2) + 4*half;
      sp[k*32 + col] = bf16rn(SA[i]);
    }
    aexA += __shfl_xor(aexA, 32, 64);
    if (l < 32) sp[1024 + l] = bf16rn(aexA);
    unsigned short* sp2 = &s_hi[(2*w+1)*SPADU];
    #pragma unroll
    for (int i=0;i<16;++i){
      int k = (i&3) + 8*(i>>2) + 4*half;
      sp2[k*32 + col] = bf16rn(SB[i]);
    }
    aexB += __shfl_xor(aexB, 32, 64);
    if (l < 32) sp2[1024 + l] = bf16rn(aexB);
  }

  // ---- phase 2: C[m][f] = sum_kd S[m][kd]*Vr[kd][f], 33 K-steps / 8 waves ----
  int fc = l & 15, hq = l >> 4;
  {
    const unsigned short* arow = &s_hi[fc*SPADU];
    const unsigned short* bh0p = VrT_hi + fc*1056;
    const unsigned short* bl0p = VrT_lo + fc*1056;
    const unsigned short* bh1p = VrT_hi + (16+fc)*1056;
    const unsigned short* bl1p = VrT_lo + (16+fc)*1056;
    f32x4 acc0 = {0.f,0.f,0.f,0.f}, acc1 = {0.f,0.f,0.f,0.f};
    int s_lo = (w*33) >> 3, s_hiS = ((w+1)*33) >> 3;
    // issue first K-step's B loads BEFORE the barrier (they don't touch LDS)
    int kb0 = s_lo*32 + hq*8;
    short8 bh0c = ld8(bh0p + kb0), bl0c = ld8(bl0p + kb0);
    short8 bh1c = ld8(bh1p + kb0), bl1c = ld8(bl1p + kb0);
    __syncthreads();
    for (int st = s_lo; st < s_hiS; ++st){
      short8 bh0n, bl0n, bh1n, bl1n;
      bool more = (st + 1) < s_hiS;
      if (more){
        int kb2 = (st+1)*32 + hq*8;
        bh0n = ld8(bh0p + kb2); bl0n = ld8(bl0p + kb2);
        bh1n = ld8(bh1p + kb2); bl1n = ld8(bl1p + kb2);
      }
      int kb = st*32 + hq*8;
      short8 Ah = *(const short8*)(arow + kb);     // direct bf16 A fragment
      acc0 = __builtin_amdgcn_mfma_f32_16x16x32_bf16(Ah, bh0c, acc0, 0,0,0);
      acc0 = __builtin_amdgcn_mfma_f32_16x16x32_bf16(Ah, bl0c, acc0, 0,0,0);
      acc1 = __builtin_amdgcn_mfma_f32_16x16x32_bf16(Ah, bh1c, acc1, 0,0,0);
      acc1 = __builtin_amdgcn_mfma_f32_16x16x32_bf16(Ah, bl1c, acc1, 0,0,0);
      if (more){ bh0c = bh0n; bl0c = bl0n; bh1c = bh1n; bl1c = bl1n; }
    }
    __syncthreads();                     // all s_hi reads done
    float* pbuf = (float*)s_hi;          // reuse: [w][m(16)][32] = 16KB
    #pragma unroll
    for (int i=0;i<4;++i){
      int m = hq*4 + i;
      pbuf[(w*16 + m)*32 + fc]      = acc0[i];
      pbuf[(w*16 + m)*32 + 16 + fc] = acc1[i];
    }
  }
  __syncthreads();

  // ---- epilogue: reduce partials, root+relu -> m, then GRU ----
  int node = t >> 5, f = t & 31;
  int n2 = nb + node;
  const float* pbuf = (const float*)s_hi;
  if (n2 < N){
    float msum = 0.f;
    #pragma unroll
    for (int w2=0; w2<8; ++w2) msum += pbuf[(w2*16 + node)*32 + f];
    float deg = (float)max(row_off[n2+1] - row_off[n2], 1);
    float rt = 0.f;
    const float4* rT4 = (const float4*)(rootT + f*32);
    const float4* h4  = (const float4*)(htile + node*32);
    #pragma unroll
    for (int k4=0;k4<8;++k4){
      float4 wv = rT4[k4]; float4 hv = h4[k4];
      rt = fmaf(hv.x, wv.x, rt); rt = fmaf(hv.y, wv.y, rt);
      rt = fmaf(hv.z, wv.z, rt); rt = fmaf(hv.w, wv.w, rt);
    }
    mtile[node*32 + f] = fmaxf(msum/deg + rt + conv_b[f], 0.f);
  }
  __syncthreads();
  if (n2 < N){
    float gr = bih[f], gz = bih[32+f], gn = bih[64+f];
    float hr = bhh[f], hz = bhh[32+f], hn = bhh[64+f];
    const float4* m4 = (const float4*)(mtile + node*32);
    const float4* h4 = (const float4*)(htile + node*32);
    const float4* w0 = (const float4*)(gruT + (0*32+f)*32);
    const float4* w1 = (const float4*)(gruT + (1*32+f)*32);
    const float4* w2 = (const float4*)(gruT + (2*32+f)*32);
    const float4* u0 = (const float4*)(gruT + 3072 + (0*32+f)*32);
    const float4* u1 = (const float4*)(gruT + 3072 + (1*32+f)*32);
    const float4* u2 = (const float4*)(gruT + 3072 + (2*32+f)*32);
    #pragma unroll
    for (int k4=0;k4<8;++k4){
      float4 mv = m4[k4], hv = h4[k4];
      float4 a0 = w0[k4], a1 = w1[k4], a2 = w2[k4];
      float4 b0 = u0[k4], b1 = u1[k4], b2 = u2[k4];
      gr = fmaf(mv.x,a0.x,gr); gr = fmaf(mv.y,a0.y,gr); gr = fmaf(mv.z,a0.z,gr); gr = fmaf(mv.w,a0.w,gr);
      gz = fmaf(mv.x,a1.x,gz); gz = fmaf(mv.y,a1.y,gz); gz = fmaf(mv.z,a1.z,gz); gz = fmaf(mv.w,a1.w,gz);
      gn = fmaf(mv.x,a2.x,gn); gn = fmaf(mv.y,a2.y,gn); gn = fmaf(mv.z,a2.z,gn); gn = fmaf(mv.w,a2.w,gn);
      hr = fmaf(hv.x,b0.x,hr); hr = fmaf(hv.y,b0.y,hr); hr = fmaf(hv.z,b0.z,hr); hr = fmaf(hv.w,b0.w,hr);
      hz = fmaf(hv.x,b1.x,hz); hz = fmaf(hv.y,b1.y,hz); hz = fmaf(hv.z,b1.z,hz); hz = fmaf(hv.w,b1.w,hz);
      hn = fmaf(hv.x,b2.x,hn); hn = fmaf(hv.y,b2.y,hn); hn = fmaf(hv.z,b2.z,hn); hn = fmaf(hv.w,b2.w,hn);
    }
    float r = sigf(gr + hr);
    float z = sigf(gz + hz);
    float nn2 = tanhf(gn + r*hn);
    float hcur = htile[node*32 + f];
    float nv = (1.f - z)*nn2 + z*hcur;
    cur_out[n2*32 + f] = nv;
    curq_out[n2*32 + f] = packsplit(nv);
  }
}

// Set2Set x6 + memory LSTM + FC head; one 512-thread block per graph.
#define S2S_CAP 480
__global__ __launch_bounds__(512) void k_s2s(
    const float* __restrict__ cur,
    const float* __restrict__ wi, const float* __restrict__ wh, const float* __restrict__ sb,
    const float* __restrict__ mwi, const float* __restrict__ mwh, const float* __restrict__ mb,
    const float* __restrict__ hx, const float* __restrict__ cx,
    const float* __restrict__ f1w, const float* __restrict__ f1b,
    const float* __restrict__ f2w, const float* __restrict__ f2b,
    float* __restrict__ out, int N, int G){
  int g = blockIdx.x, t = threadIdx.x;
  int lo = (int)(((long long)g*N + G - 1)/G);
  int hi = (int)(((long long)(g+1)*N + G - 1)/G);
  int cnt = hi - lo;
  __shared__ float curL[S2S_CAP*33];
  __shared__ float wiL[96*128];
  __shared__ float ebuf[S2S_CAP];
  __shared__ float qh[96];
  __shared__ float csS[32];
  __shared__ float gbuf[128];
  __shared__ float pbuf4[4][128];
  __shared__ float redr[8*32];
  __shared__ float smax[8], ssum[8];
  __shared__ float bmaxS, bsumS;
  __shared__ float hnew[32], f1o[32];
  for (int i = t; i < cnt*32; i += 512){
    int p = i >> 5, d2 = i & 31;
    curL[p*33 + d2] = cur[(size_t)(lo + p)*32 + d2];
  }
  for (int i = t; i < 96*128; i += 512){
    int j = i >> 7, o = i & 127;
    wiL[i] = (j < 64) ? wi[j*128 + o] : wh[(j-64)*128 + o];
  }
  if (t < 96) qh[t] = 0.f;
  if (t < 32) csS[t] = 0.f;
  __syncthreads();
  int wv = t >> 6, l = t & 63, d = l & 31, halfw = l >> 5;
  int p0 = wv*2 + halfw;
  for (int it = 0; it < 6; ++it){
    {
      int o = t & 127, part = t >> 7;
      const float* wp = &wiL[part*24*128 + o];
      const float* qp = &qh[part*24];
      float a = 0.f;
      #pragma unroll
      for (int jj=0;jj<24;++jj) a = fmaf(qp[jj], wp[jj*128], a);
      pbuf4[part][o] = a;
    }
    __syncthreads();
    if (t < 128) gbuf[t] = pbuf4[0][t]+pbuf4[1][t]+pbuf4[2][t]+pbuf4[3][t] + sb[t];
    __syncthreads();
    if (t < 32){
      float c = sigf(gbuf[32+t])*csS[t] + sigf(gbuf[t])*tanhf(gbuf[64+t]);
      csS[t] = c;
      qh[64+t] = sigf(gbuf[96+t])*tanhf(c);
    }
    __syncthreads();
    float lmax = -3.4e38f;
    for (int p = t; p < cnt; p += 512){
      float acc = 0.f;
      #pragma unroll
      for (int d2=0; d2<32; ++d2) acc = fmaf(curL[p*33 + d2], qh[64+d2], acc);
      ebuf[p] = acc;
      lmax = fmaxf(lmax, acc);
    }
    #pragma unroll
    for (int o2 = 1; o2 < 64; o2 <<= 1) lmax = fmaxf(lmax, __shfl_xor(lmax, o2, 64));
    if (l == 0) smax[wv] = lmax;
    __syncthreads();
    if (t == 0){ float mm = smax[0]; for (int i=1;i<8;++i) mm = fmaxf(mm, smax[i]); bmaxS = mm; }
    __syncthreads();
    float bmax = bmaxS;
    float lsum = 0.f;
    for (int p = t; p < cnt; p += 512){
      float a = expf(ebuf[p] - bmax);
      ebuf[p] = a;
      lsum += a;
    }
    #pragma unroll
    for (int o2 = 1; o2 < 64; o2 <<= 1) lsum += __shfl_xor(lsum, o2, 64);
    if (l == 0) ssum[wv] = lsum;
    __syncthreads();
    if (t == 0){ float s2 = 0.f; for (int i=0;i<8;++i) s2 += ssum[i]; bsumS = s2; }
    __syncthreads();
    float racc = 0.f;
    for (int p = p0; p < cnt; p += 16)
      racc = fmaf(ebuf[p], curL[p*33 + d], racc);
    racc += __shfl_xor(racc, 32, 64);
    if (l < 32) redr[wv*32 + l] = racc;
    __syncthreads();
    if (t < 32){
      float rsum = 0.f;
      #pragma unroll
      for (int w2=0; w2<8; ++w2) rsum += redr[w2*32 + t];
      qh[t] = qh[64+t];
      qh[32 + t] = rsum / bsumS;
    }
    __syncthreads();
  }
  if (t < 128){
    float acc = mb[t];
    for (int j=0;j<64;++j) acc = fmaf(qh[j], mwi[j*128+t], acc);
    for (int j=0;j<32;++j) acc = fmaf(hx[g*32+j], mwh[j*128+t], acc);
    gbuf[t] = acc;
  }
  __syncthreads();
  if (t < 32){
    float c = sigf(gbuf[32+t])*cx[g*32+t] + sigf(gbuf[t])*tanhf(gbuf[64+t]);
    float h = sigf(gbuf[96+t])*tanhf(c);
    out[G + g*32 + t] = h;
    out[G + G*32 + g*32 + t] = c;
    hnew[t] = h;
  }
  __syncthreads();
  if (t < 32){
    float acc = f1b[t];
    #pragma unroll
    for (int k=0;k<32;++k) acc = fmaf(hnew[k], f1w[k*32+t], acc);
    f1o[t] = fmaxf(acc, 0.f);
  }
  __syncthreads();
  if (t == 0){
    float acc = f2b[0];
    #pragma unroll
    for (int k=0;k<32;++k) acc = fmaf(f1o[k], f2w[k], acc);
    out[g] = acc;
  }
}

extern "C" void kernel_launch(void* const* d_in, const int* in_sizes, int n_in,
                              void* d_out, int out_size, void* d_ws, size_t ws_size,
                              hipStream_t stream) {
  const float* x      = (const float*)d_in[0];
  const float* ea     = (const float*)d_in[1];
  const float* hx     = (const float*)d_in[2];
  const float* cx     = (const float*)d_in[3];
  const float* lin0_w = (const float*)d_in[4];
  const float* lin0_b = (const float*)d_in[5];
  const float* e_w1   = (const float*)d_in[6];
  const float* e_b1   = (const float*)d_in[7];
  const float* e_w2   = (const float*)d_in[8];
  const float* e_b2   = (const float*)d_in[9];
  const float* root_w = (const float*)d_in[10];
  const float* conv_b = (const float*)d_in[11];
  const float* g_wih  = (const float*)d_in[12];
  const float* g_whh  = (const float*)d_in[13];
  const float* g_bih  = (const float*)d_in[14];
  const float* g_bhh  = (const float*)d_in[15];
  const float* s_wi   = (const float*)d_in[16];
  const float* s_wh   = (const float*)d_in[17];
  const float* s_b    = (const float*)d_in[18];
  const float* m_wi   = (const float*)d_in[19];
  const float* m_wh   = (const float*)d_in[20];
  const float* m_b    = (const float*)d_in[21];
  const float* f1w    = (const float*)d_in[22];
  const float* f1b    = (const float*)d_in[23];
  const float* f2w    = (const float*)d_in[24];
  const float* f2b    = (const float*)d_in[25];
  const int*   eidx   = (const int*)d_in[26];
  int N = in_sizes[0]/3;
  int E = in_sizes[1]/4;
  int G = in_sizes[2]/32;
  const int* srcI = eidx;
  const int* dstI = eidx + E;
  float* outF = (float*)d_out;

  char* wbase = (char*)d_ws; size_t off = 0;
  auto carve = [&](size_t nbytes)->char*{
    char* p = wbase + off; off = (off + nbytes + 255) & ~(size_t)255; return p;
  };
  float* cur0    = (float*)carve((size_t)N*32*4);
  float* cur1    = (float*)carve((size_t)N*32*4);
  unsigned* curq0 = (unsigned*)carve((size_t)N*32*4);
  unsigned* curq1 = (unsigned*)carve((size_t)N*32*4);
  unsigned* hidq = (unsigned*)carve((size_t)E*32*4);
  unsigned short* VrT_hi = (unsigned short*)carve((size_t)1056*32*2);
  unsigned short* VrT_lo = (unsigned short*)carve((size_t)1056*32*2);
  float* gruT    = (float*)carve((size_t)6144*4);
  float* rootT   = (float*)carve((size_t)1024*4);
  int*   counts  = (int*)carve((size_t)N*4);
  int*   cursor  = (int*)carve((size_t)N*4);
  int*   row_off = (int*)carve((size_t)(N+1)*4);
  int*   eid     = (int*)carve((size_t)E*4);
  int*   srcp    = (int*)carve((size_t)E*4);
  int*   part    = (int*)carve((size_t)256*4);
  (void)ws_size; (void)n_in; (void)out_size;

  int nch = (N + 255)/256;

  // phase A: fused pre, CSR build with parallel scan
  k_pre<<<(N*32+255)/256, 256, 0, stream>>>(x, lin0_w, lin0_b, e_w2, e_b2,
                                            g_wih, g_whh, root_w,
                                            cur0, curq0, VrT_hi, VrT_lo,
                                            gruT, rootT, counts, cursor, N);
  k_count<<<(E+255)/256, 256, 0, stream>>>(dstI, counts, E);
  k_scanA<<<nch, 256, 0, stream>>>(counts, row_off, part, N);
  k_scanB<<<1, 256, 0, stream>>>(part, row_off, nch, N);
  k_scanC<<<nch, 256, 0, stream>>>(row_off, part, N);
  k_scatter<<<(E+255)/256, 256, 0, stream>>>(dstI, row_off, cursor, eid, E);
  k_edgeCSR<<<(E*32+255)/256, 256, 0, stream>>>(eid, srcI, ea, e_w1, e_b1, hidq, srcp, E);

  // phase B: 6 fused message-passing + GRU iterations (ping-pong cur/curq)
  float* cin = cur0; float* cout = cur1;
  unsigned* qin = curq0; unsigned* qout = curq1;
  for (int it = 0; it < 6; ++it){
    k_iter<<<(N+15)/16, 512, 0, stream>>>(row_off, srcp, hidq, qin, cin,
                                          VrT_hi, VrT_lo, gruT, rootT, conv_b,
                                          g_bih, g_bhh, cout, qout, N);
    float* tf = cin; cin = cout; cout = tf;
    unsigned* tq = qin; qin = qout; qout = tq;
  }

  // phase C+D: Set2Set x6 + memory LSTM + FC head
  k_s2s<<<G, 512, 0, stream>>>(cin, s_wi, s_wh, s_b, m_wi, m_wh, m_b,
                               hx, cx, f1w, f1b, f2w, f2b, outF, N, G);
}